// Round 13
// baseline (296.246 us; speedup 1.0000x reference)
//
#include <hip/hip_runtime.h>

#define N_NODES 100000
#define N_EDGES 1600000
#define NBUCK 391      // ceil(100000/256) coarse buckets
#define BSH 8          // 256 nodes per bucket
#define EPT 64         // edges per thread-slot in bucket phase (16384 edges/block, 98 blocks)
#define SLAB_SH 13     // 8192-edge slab per bucket (mean 4096, sigma ~64)

typedef __attribute__((ext_vector_type(8))) short short8;
typedef __attribute__((ext_vector_type(4))) float f32x4;

__device__ __forceinline__ float bflo(unsigned int u) { return __uint_as_float(u << 16); }
__device__ __forceinline__ float bfhi(unsigned int u) { return __uint_as_float(u & 0xffff0000u); }
__device__ __forceinline__ float bf2f(unsigned short u) { return __uint_as_float(((unsigned int)u) << 16); }
__device__ __forceinline__ unsigned short f2bf(float f) {
    unsigned int u = __float_as_uint(f);
    return (unsigned short)((u + 0x7fffu + ((u >> 16) & 1u)) >> 16);   // RNE
}

// ================= mega-pre: cast x->bf16 | slab counting-sort | weight prepack =================
// ccnt[] holds per-bucket edge COUNTS (zeroed by memset); slab base = bkt<<SLAB_SH.
__global__ __launch_bounds__(256) void k_pre(
    const float* __restrict__ x, unsigned short* __restrict__ xh,
    const int* __restrict__ src, const int* __restrict__ dst,
    int* __restrict__ ccnt, unsigned int* __restrict__ pairs,
    const float* __restrict__ Wl1, const float* __restrict__ Wr1,
    const float* __restrict__ Wl2, const float* __restrict__ Wr2,
    unsigned short* __restrict__ Bp1, unsigned short* __restrict__ Bp2)
{
    __shared__ int cnt[NBUCK];
    __shared__ int base[NBUCK];
    const int tid = threadIdx.x;
    if (blockIdx.x < 6250) {                        // ---- cast x (1.6M threads x 4 floats)
        int i = blockIdx.x * 256 + tid;
        float4 v = *reinterpret_cast<const float4*>(x + (size_t)i * 4);
        ushort4 o;
        o.x = f2bf(v.x); o.y = f2bf(v.y); o.z = f2bf(v.z); o.w = f2bf(v.w);
        *reinterpret_cast<ushort4*>(xh + (size_t)i * 4) = o;
    } else if (blockIdx.x < 6348) {                 // ---- slab bucket sort (98 blocks x 16384 edges)
        const int e_base = (blockIdx.x - 6250) * (256 * EPT);
        for (int i = tid; i < NBUCK; i += 256) cnt[i] = 0;
        __syncthreads();
        #pragma unroll
        for (int i = 0; i < EPT; ++i) {              // phase A: local histogram
            int e = e_base + i * 256 + tid;
            if (e < N_EDGES) atomicAdd(&cnt[dst[e] >> BSH], 1);
        }
        __syncthreads();
        for (int i = tid; i < NBUCK; i += 256) {     // phase B: reserve slab ranges
            int c = cnt[i];
            int r = (c > 0) ? atomicAdd(&ccnt[i], c) : 0;
            base[i] = (i << SLAB_SH) + r;
            cnt[i] = 0;
        }
        __syncthreads();
        #pragma unroll
        for (int i = 0; i < EPT; ++i) {              // phase C: grouped scatter
            int e = e_base + i * 256 + tid;
            if (e < N_EDGES) {
                int d = dst[e];
                int bkt = d >> BSH;
                int off = atomicAdd(&cnt[bkt], 1);
                pairs[base[bkt] + off] = ((unsigned int)(d & 255) << 17) | (unsigned int)src[e];
            }
        }
    } else {                                        // ---- weight prepack (192 blocks)
        int idx = (blockIdx.x - 6348) * 256 + tid;
        if (idx < 16384) {                          // layer1: K=128
            int j = idx & 7, g = (idx >> 3) & 3, col = (idx >> 5) & 127, kk = idx >> 12;
            int r = kk * 32 + g * 8 + j;
            float w = (r < 64) ? Wl1[r * 128 + col] : Wr1[(r - 64) * 128 + col];
            Bp1[idx] = f2bf(w);
        } else {                                    // layer2: K=256
            int q = idx - 16384;
            int j = q & 7, g = (q >> 3) & 3, col = (q >> 5) & 127, kk = q >> 12;
            int r = kk * 32 + g * 8 + j;
            float w = (r < 128) ? Wl2[r * 128 + col] : Wr2[(r - 128) * 128 + col];
            Bp2[q] = f2bf(w);
        }
    }
}

// ================= CSR: per-bucket hist + scan -> rowpad[391*257]; exact scatter to srcs slab =================
__global__ __launch_bounds__(256) void k_csr(const int* __restrict__ ccnt,
                                             const unsigned int* __restrict__ pairs,
                                             int* __restrict__ rowpad, int* __restrict__ srcs) {
    __shared__ int nh[256];       // per-node counts -> cursors
    __shared__ int wsum[4];
    const int c = blockIdx.x, tid = threadIdx.x, lane = tid & 63, wid = tid >> 6;
    const int e0 = c << SLAB_SH, e1 = e0 + ccnt[c];

    nh[tid] = 0;
    __syncthreads();
    for (int e = e0 + tid; e < e1; e += 256)     // phase A: node histogram from pairs
        atomicAdd(&nh[pairs[e] >> 17], 1);
    __syncthreads();
    int v = nh[tid];                              // phase B: scan 256 counts
    int s = v;
    #pragma unroll
    for (int off = 1; off < 64; off <<= 1) {
        int t = __shfl_up(s, off);
        if (lane >= off) s += t;
    }
    if (lane == 63) wsum[wid] = s;
    __syncthreads();
    if (tid < 4) {
        int w = wsum[tid];
        #pragma unroll
        for (int off = 1; off < 4; off <<= 1) {
            int t = __shfl_up(w, off);
            if (tid >= off) w += t;
        }
        wsum[tid] = w;
    }
    __syncthreads();
    int excl = e0 + ((wid == 0) ? 0 : wsum[wid - 1]) + s - v;
    rowpad[c * 257 + tid] = excl;                 // coalesced rowstart write (bucket-local CSR)
    if (tid == 0) rowpad[c * 257 + 256] = e1;     // bucket end sentinel
    __syncthreads();
    nh[tid] = excl;                               // reuse as cursors
    __syncthreads();
    for (int e = e0 + tid; e < e1; e += 256) {    // phase C: exact scatter (LDS cursors, L2-hot)
        unsigned int u = pairs[e];
        int p = atomicAdd(&nh[u >> 17], 1);
        srcs[p] = (int)(u & 0x1FFFFu);
    }
}

// ================= layer 1: gather(bf16, unroll-8) + MFMA dense + relu -> bf16 h1h =================
__global__ __launch_bounds__(256, 8) void k_layer1(
    const unsigned short* __restrict__ xh,
    const int* __restrict__ rowpad, const int* __restrict__ srcs,
    const unsigned short* __restrict__ Bp1, const float* __restrict__ b,
    unsigned short* __restrict__ h1h)
{
    __shared__ unsigned short A[32][136];
    __shared__ int rs[33];
    const int tile = blockIdx.x * 32;           // 100000 = 3125*32
    const int tid = threadIdx.x, lane = tid & 63, wid = tid >> 6;

    if (tid < 33) rs[tid] = rowpad[(tile >> 8) * 257 + (tile & 255) + tid];
    {   // root rows -> cols 64..127
        int node = tid >> 3, part = tid & 7;
        uint4 v = *reinterpret_cast<const uint4*>(xh + (size_t)(tile + node) * 64 + part * 8);
        *reinterpret_cast<uint4*>(&A[node][64 + part * 8]) = v;
    }
    __syncthreads();

    for (int it = 0; it < 8; ++it) {            // wave-per-node gather, unroll-8
        int nl = wid * 8 + it;
        int e0 = rs[nl], e1 = rs[nl + 1];
        float a0 = 0.f, a1 = 0.f, a2 = 0.f, a3 = 0.f;
        int e = e0;
        for (; e + 8 <= e1; e += 8) {
            int s0 = __builtin_nontemporal_load(srcs + e);
            int s1 = __builtin_nontemporal_load(srcs + e + 1);
            int s2 = __builtin_nontemporal_load(srcs + e + 2);
            int s3 = __builtin_nontemporal_load(srcs + e + 3);
            int s4 = __builtin_nontemporal_load(srcs + e + 4);
            int s5 = __builtin_nontemporal_load(srcs + e + 5);
            int s6 = __builtin_nontemporal_load(srcs + e + 6);
            int s7 = __builtin_nontemporal_load(srcs + e + 7);
            float v0 = bf2f(xh[(size_t)s0 * 64 + lane]);
            float v1 = bf2f(xh[(size_t)s1 * 64 + lane]);
            float v2 = bf2f(xh[(size_t)s2 * 64 + lane]);
            float v3 = bf2f(xh[(size_t)s3 * 64 + lane]);
            float v4 = bf2f(xh[(size_t)s4 * 64 + lane]);
            float v5 = bf2f(xh[(size_t)s5 * 64 + lane]);
            float v6 = bf2f(xh[(size_t)s6 * 64 + lane]);
            float v7 = bf2f(xh[(size_t)s7 * 64 + lane]);
            a0 += v0; a1 += v1; a2 += v2; a3 += v3;
            a0 += v4; a1 += v5; a2 += v6; a3 += v7;
        }
        for (; e < e1; ++e)
            a0 += bf2f(xh[(size_t)srcs[e] * 64 + lane]);
        float acc = (a0 + a1) + (a2 + a3);
        int d = e1 - e0;
        A[nl][lane] = f2bf(acc * ((d > 0) ? (1.0f / (float)d) : 1.0f));
    }
    __syncthreads();

    const int r15 = lane & 15, g4 = lane >> 4;
    const int n0 = wid * 32;
    f32x4 acc[2][2] = {};
    for (int kk = 0; kk < 4; ++kk) {
        short8 b0 = *reinterpret_cast<const short8*>(Bp1 + (((kk * 128 + n0 + r15) * 4 + g4) << 3));
        short8 b1 = *reinterpret_cast<const short8*>(Bp1 + (((kk * 128 + n0 + 16 + r15) * 4 + g4) << 3));
        #pragma unroll
        for (int mt = 0; mt < 2; ++mt) {
            short8 a = *reinterpret_cast<const short8*>(&A[mt * 16 + r15][kk * 32 + g4 * 8]);
            acc[mt][0] = __builtin_amdgcn_mfma_f32_16x16x32_bf16(a, b0, acc[mt][0], 0, 0, 0);
            acc[mt][1] = __builtin_amdgcn_mfma_f32_16x16x32_bf16(a, b1, acc[mt][1], 0, 0, 0);
        }
    }
    #pragma unroll
    for (int mt = 0; mt < 2; ++mt)
        #pragma unroll
        for (int nt = 0; nt < 2; ++nt) {
            int col = n0 + nt * 16 + r15;
            float bb = b[col];
            #pragma unroll
            for (int reg = 0; reg < 4; ++reg) {
                int row = tile + mt * 16 + g4 * 4 + reg;
                h1h[(size_t)row * 128 + col] = f2bf(fmaxf(acc[mt][nt][reg] + bb, 0.0f));
            }
        }
}

// ================= layer 2 + heads: gather(bf16x2, unroll-8) + MFMA dense + relu + heads =================
__global__ __launch_bounds__(256, 8) void k_layer2(
    const unsigned int* __restrict__ h1h32,
    const int* __restrict__ rowpad, const int* __restrict__ srcs,
    const unsigned short* __restrict__ Bp2, const float* __restrict__ b,
    const float* __restrict__ Wh, const float* __restrict__ bh,
    const float* __restrict__ Wm, const float* __restrict__ bm,
    float* __restrict__ out1, float* __restrict__ out2)
{
    __shared__ unsigned short A[32][264];
    __shared__ int rs[33];
    const int tile = blockIdx.x * 32;
    const int tid = threadIdx.x, lane = tid & 63, wid = tid >> 6;

    if (tid < 33) rs[tid] = rowpad[(tile >> 8) * 257 + (tile & 255) + tid];
    {   // root rows -> cols 128..255
        int node = tid >> 3, part = tid & 7;
        const unsigned int* p = h1h32 + (size_t)(tile + node) * 64 + part * 8;
        uint4 v0 = *reinterpret_cast<const uint4*>(p);
        uint4 v1 = *reinterpret_cast<const uint4*>(p + 4);
        *reinterpret_cast<uint4*>(&A[node][128 + part * 16]) = v0;
        *reinterpret_cast<uint4*>(&A[node][128 + part * 16 + 8]) = v1;
    }
    __syncthreads();

    for (int it = 0; it < 8; ++it) {            // wave-per-node gather, unroll-8
        int nl = wid * 8 + it;
        int e0 = rs[nl], e1 = rs[nl + 1];
        float ax0 = 0.f, ax1 = 0.f, ax2 = 0.f, ax3 = 0.f;
        float ay0 = 0.f, ay1 = 0.f, ay2 = 0.f, ay3 = 0.f;
        int e = e0;
        for (; e + 8 <= e1; e += 8) {
            int s0 = __builtin_nontemporal_load(srcs + e);
            int s1 = __builtin_nontemporal_load(srcs + e + 1);
            int s2 = __builtin_nontemporal_load(srcs + e + 2);
            int s3 = __builtin_nontemporal_load(srcs + e + 3);
            int s4 = __builtin_nontemporal_load(srcs + e + 4);
            int s5 = __builtin_nontemporal_load(srcs + e + 5);
            int s6 = __builtin_nontemporal_load(srcs + e + 6);
            int s7 = __builtin_nontemporal_load(srcs + e + 7);
            unsigned int u0 = h1h32[(size_t)s0 * 64 + lane];
            unsigned int u1 = h1h32[(size_t)s1 * 64 + lane];
            unsigned int u2 = h1h32[(size_t)s2 * 64 + lane];
            unsigned int u3 = h1h32[(size_t)s3 * 64 + lane];
            unsigned int u4 = h1h32[(size_t)s4 * 64 + lane];
            unsigned int u5 = h1h32[(size_t)s5 * 64 + lane];
            unsigned int u6 = h1h32[(size_t)s6 * 64 + lane];
            unsigned int u7 = h1h32[(size_t)s7 * 64 + lane];
            ax0 += bflo(u0); ay0 += bfhi(u0);
            ax1 += bflo(u1); ay1 += bfhi(u1);
            ax2 += bflo(u2); ay2 += bfhi(u2);
            ax3 += bflo(u3); ay3 += bfhi(u3);
            ax0 += bflo(u4); ay0 += bfhi(u4);
            ax1 += bflo(u5); ay1 += bfhi(u5);
            ax2 += bflo(u6); ay2 += bfhi(u6);
            ax3 += bflo(u7); ay3 += bfhi(u7);
        }
        for (; e < e1; ++e) {
            unsigned int u = h1h32[(size_t)srcs[e] * 64 + lane];
            ax0 += bflo(u); ay0 += bfhi(u);
        }
        float ax = (ax0 + ax1) + (ax2 + ax3);
        float ay = (ay0 + ay1) + (ay2 + ay3);
        int d = e1 - e0;
        float rd = (d > 0) ? (1.0f / (float)d) : 1.0f;
        unsigned int p = (unsigned int)f2bf(ax * rd) | ((unsigned int)f2bf(ay * rd) << 16);
        *reinterpret_cast<unsigned int*>(&A[nl][2 * lane]) = p;
    }
    __syncthreads();

    const int r15 = lane & 15, g4 = lane >> 4;
    const int n0 = wid * 32;
    f32x4 acc[2][2] = {};
    for (int kk = 0; kk < 8; ++kk) {
        short8 b0 = *reinterpret_cast<const short8*>(Bp2 + (((kk * 128 + n0 + r15) * 4 + g4) << 3));
        short8 b1 = *reinterpret_cast<const short8*>(Bp2 + (((kk * 128 + n0 + 16 + r15) * 4 + g4) << 3));
        #pragma unroll
        for (int mt = 0; mt < 2; ++mt) {
            short8 a = *reinterpret_cast<const short8*>(&A[mt * 16 + r15][kk * 32 + g4 * 8]);
            acc[mt][0] = __builtin_amdgcn_mfma_f32_16x16x32_bf16(a, b0, acc[mt][0], 0, 0, 0);
            acc[mt][1] = __builtin_amdgcn_mfma_f32_16x16x32_bf16(a, b1, acc[mt][1], 0, 0, 0);
        }
    }
    __syncthreads();
    float* h2L = reinterpret_cast<float*>(&A[0][0]);   // [32][132]
    #pragma unroll
    for (int mt = 0; mt < 2; ++mt)
        #pragma unroll
        for (int nt = 0; nt < 2; ++nt) {
            int col = n0 + nt * 16 + r15;
            float bb = b[col];
            #pragma unroll
            for (int reg = 0; reg < 4; ++reg) {
                int row = mt * 16 + g4 * 4 + reg;
                h2L[row * 132 + col] = fmaxf(acc[mt][nt][reg] + bb, 0.0f);
            }
        }
    __syncthreads();

    for (int t = tid; t < 352; t += 256) {       // heads
        int node = t / 11, o = t - node * 11;
        const float* h2 = &h2L[node * 132];
        if (o < 3) {
            float s = bh[o];
            for (int k = 0; k < 128; ++k) s += h2[k] * Wh[k * 3 + o];
            out1[(size_t)(tile + node) * 3 + o] = s;
        } else {
            int m = o - 3;
            float s = bm[m];
            for (int k = 0; k < 128; ++k) s += h2[k] * Wm[k * 8 + m];
            out2[(size_t)(tile + node) * 8 + m] = s;
        }
    }
}

extern "C" void kernel_launch(void* const* d_in, const int* in_sizes, int n_in,
                              void* d_out, int out_size, void* d_ws, size_t ws_size,
                              hipStream_t stream) {
    const float* x   = (const float*)d_in[0];
    const int*   ei  = (const int*)d_in[1];
    const int*   src = ei;
    const int*   dst = ei + N_EDGES;
    const float* Wl1 = (const float*)d_in[2];
    const float* Wr1 = (const float*)d_in[3];
    const float* b1  = (const float*)d_in[4];
    const float* Wl2 = (const float*)d_in[5];
    const float* Wr2 = (const float*)d_in[6];
    const float* b2  = (const float*)d_in[7];
    const float* Wh  = (const float*)d_in[8];
    const float* bh  = (const float*)d_in[9];
    const float* Wm  = (const float*)d_in[10];
    const float* bm  = (const float*)d_in[11];

    float* out1 = (float*)d_out;                   // [N,3]
    float* out2 = out1 + (size_t)N_NODES * 3;      // [N,8]

    char* ws = (char*)d_ws;
    int*   ccnt     = (int*)(ws);                            // 391 ints (counts, memset to 0)
    int*   rowpad   = (int*)(ws + (64 << 10));               // 391*257 ints (402KB)
    unsigned int* pairs = (unsigned int*)(ws + (1024 << 10)); // 391*8192 u32 (12.5MB)
    int*   srcs     = (int*)(ws + (14336 << 10));            // 391*8192 ints (12.5MB)
    unsigned short* xh  = (unsigned short*)(ws + (27648 << 10)); // 6.4M bf16 (12.8MB)
    unsigned short* h1h = (unsigned short*)(ws + (40960 << 10)); // 12.8M bf16 (25.6MB)
    unsigned short* Bp1 = (unsigned short*)(ws + (66560 << 10)); // 16384 bf16 (32KB)
    unsigned short* Bp2 = (unsigned short*)(ws + (66592 << 10)); // 32768 bf16 (64KB)

    hipMemsetAsync(ccnt, 0, NBUCK * sizeof(int), stream);
    k_pre<<<6540, 256, 0, stream>>>(x, xh, src, dst, ccnt, pairs, Wl1, Wr1, Wl2, Wr2, Bp1, Bp2);
    k_csr<<<NBUCK, 256, 0, stream>>>(ccnt, pairs, rowpad, srcs);

    k_layer1<<<3125, 256, 0, stream>>>(xh, rowpad, srcs, Bp1, b1, h1h);
    k_layer2<<<3125, 256, 0, stream>>>((const unsigned int*)h1h, rowpad, srcs,
                                       Bp2, b2, Wh, bh, Wm, bm, out1, out2);
}

// Round 14
// 281.675 us; speedup vs baseline: 1.0517x; 1.0517x over previous
//
#include <hip/hip_runtime.h>

#define N_NODES 100000
#define N_EDGES 1600000
#define NBUCK 391      // ceil(100000/256) coarse buckets
#define BSH 8          // 256 nodes per bucket
#define EPT 64         // edges per thread-slot in bucket phase (16384 edges/block, 98 blocks)
#define SLAB_SH 13     // 8192-edge slab per bucket (mean 4096, sigma ~64)

typedef __attribute__((ext_vector_type(8))) short short8;
typedef __attribute__((ext_vector_type(4))) float f32x4;

__device__ __forceinline__ float bflo(unsigned int u) { return __uint_as_float(u << 16); }
__device__ __forceinline__ float bfhi(unsigned int u) { return __uint_as_float(u & 0xffff0000u); }
__device__ __forceinline__ float bf2f(unsigned short u) { return __uint_as_float(((unsigned int)u) << 16); }
__device__ __forceinline__ unsigned short f2bf(float f) {
    unsigned int u = __float_as_uint(f);
    return (unsigned short)((u + 0x7fffu + ((u >> 16) & 1u)) >> 16);   // RNE
}

// ================= mega-pre: cast x->bf16 | slab counting-sort | weight prepack =================
// ccnt[] holds per-bucket edge COUNTS (zeroed by memset); slab base = bkt<<SLAB_SH.
__global__ __launch_bounds__(256) void k_pre(
    const float* __restrict__ x, unsigned short* __restrict__ xh,
    const int* __restrict__ src, const int* __restrict__ dst,
    int* __restrict__ ccnt, unsigned int* __restrict__ pairs,
    const float* __restrict__ Wl1, const float* __restrict__ Wr1,
    const float* __restrict__ Wl2, const float* __restrict__ Wr2,
    unsigned short* __restrict__ Bp1, unsigned short* __restrict__ Bp2)
{
    __shared__ int cnt[NBUCK];
    __shared__ int base[NBUCK];
    const int tid = threadIdx.x;
    if (blockIdx.x < 6250) {                        // ---- cast x (1.6M threads x 4 floats)
        int i = blockIdx.x * 256 + tid;
        float4 v = *reinterpret_cast<const float4*>(x + (size_t)i * 4);
        ushort4 o;
        o.x = f2bf(v.x); o.y = f2bf(v.y); o.z = f2bf(v.z); o.w = f2bf(v.w);
        *reinterpret_cast<ushort4*>(xh + (size_t)i * 4) = o;
    } else if (blockIdx.x < 6348) {                 // ---- slab bucket sort (98 blocks x 16384 edges)
        const int e_base = (blockIdx.x - 6250) * (256 * EPT);
        for (int i = tid; i < NBUCK; i += 256) cnt[i] = 0;
        __syncthreads();
        #pragma unroll
        for (int i = 0; i < EPT; ++i) {              // phase A: local histogram
            int e = e_base + i * 256 + tid;
            if (e < N_EDGES) atomicAdd(&cnt[dst[e] >> BSH], 1);
        }
        __syncthreads();
        for (int i = tid; i < NBUCK; i += 256) {     // phase B: reserve slab ranges
            int c = cnt[i];
            int r = (c > 0) ? atomicAdd(&ccnt[i], c) : 0;
            base[i] = (i << SLAB_SH) + r;
            cnt[i] = 0;
        }
        __syncthreads();
        #pragma unroll
        for (int i = 0; i < EPT; ++i) {              // phase C: grouped scatter
            int e = e_base + i * 256 + tid;
            if (e < N_EDGES) {
                int d = dst[e];
                int bkt = d >> BSH;
                int off = atomicAdd(&cnt[bkt], 1);
                pairs[base[bkt] + off] = ((unsigned int)(d & 255) << 17) | (unsigned int)src[e];
            }
        }
    } else {                                        // ---- weight prepack (192 blocks)
        int idx = (blockIdx.x - 6348) * 256 + tid;
        if (idx < 16384) {                          // layer1: K=128
            int j = idx & 7, g = (idx >> 3) & 3, col = (idx >> 5) & 127, kk = idx >> 12;
            int r = kk * 32 + g * 8 + j;
            float w = (r < 64) ? Wl1[r * 128 + col] : Wr1[(r - 64) * 128 + col];
            Bp1[idx] = f2bf(w);
        } else {                                    // layer2: K=256
            int q = idx - 16384;
            int j = q & 7, g = (q >> 3) & 3, col = (q >> 5) & 127, kk = q >> 12;
            int r = kk * 32 + g * 8 + j;
            float w = (r < 128) ? Wl2[r * 128 + col] : Wr2[(r - 128) * 128 + col];
            Bp2[q] = f2bf(w);
        }
    }
}

// ================= CSR: per-bucket hist + scan -> rowpad[391*257]; exact scatter to srcs slab =================
__global__ __launch_bounds__(256) void k_csr(const int* __restrict__ ccnt,
                                             const unsigned int* __restrict__ pairs,
                                             int* __restrict__ rowpad, int* __restrict__ srcs) {
    __shared__ int nh[256];       // per-node counts -> cursors
    __shared__ int wsum[4];
    const int c = blockIdx.x, tid = threadIdx.x, lane = tid & 63, wid = tid >> 6;
    const int e0 = c << SLAB_SH, e1 = e0 + ccnt[c];

    nh[tid] = 0;
    __syncthreads();
    for (int e = e0 + tid; e < e1; e += 256)     // phase A: node histogram from pairs
        atomicAdd(&nh[pairs[e] >> 17], 1);
    __syncthreads();
    int v = nh[tid];                              // phase B: scan 256 counts
    int s = v;
    #pragma unroll
    for (int off = 1; off < 64; off <<= 1) {
        int t = __shfl_up(s, off);
        if (lane >= off) s += t;
    }
    if (lane == 63) wsum[wid] = s;
    __syncthreads();
    if (tid < 4) {
        int w = wsum[tid];
        #pragma unroll
        for (int off = 1; off < 4; off <<= 1) {
            int t = __shfl_up(w, off);
            if (tid >= off) w += t;
        }
        wsum[tid] = w;
    }
    __syncthreads();
    int excl = e0 + ((wid == 0) ? 0 : wsum[wid - 1]) + s - v;
    rowpad[c * 257 + tid] = excl;                 // coalesced rowstart write (bucket-local CSR)
    if (tid == 0) rowpad[c * 257 + 256] = e1;     // bucket end sentinel
    __syncthreads();
    nh[tid] = excl;                               // reuse as cursors
    __syncthreads();
    for (int e = e0 + tid; e < e1; e += 256) {    // phase C: exact scatter (LDS cursors, L2-hot)
        unsigned int u = pairs[e];
        int p = atomicAdd(&nh[u >> 17], 1);
        srcs[p] = (int)(u & 0x1FFFFu);
    }
}

// ================= layer 1: gather(bf16, unroll-8) + MFMA dense + relu -> bf16 h1h =================
__global__ __launch_bounds__(256, 8) void k_layer1(
    const unsigned short* __restrict__ xh,
    const int* __restrict__ rowpad, const int* __restrict__ srcs,
    const unsigned short* __restrict__ Bp1, const float* __restrict__ b,
    unsigned short* __restrict__ h1h)
{
    __shared__ unsigned short A[32][136];
    __shared__ int rs[33];
    const int tile = blockIdx.x * 32;           // 100000 = 3125*32
    const int tid = threadIdx.x, lane = tid & 63, wid = tid >> 6;

    if (tid < 33) rs[tid] = rowpad[(tile >> 8) * 257 + (tile & 255) + tid];
    {   // root rows -> cols 64..127
        int node = tid >> 3, part = tid & 7;
        uint4 v = *reinterpret_cast<const uint4*>(xh + (size_t)(tile + node) * 64 + part * 8);
        *reinterpret_cast<uint4*>(&A[node][64 + part * 8]) = v;
    }
    __syncthreads();

    for (int it = 0; it < 8; ++it) {            // wave-per-node gather, unroll-8
        int nl = wid * 8 + it;
        int e0 = rs[nl], e1 = rs[nl + 1];
        float a0 = 0.f, a1 = 0.f, a2 = 0.f, a3 = 0.f;
        int e = e0;
        for (; e + 8 <= e1; e += 8) {
            int s0 = srcs[e],     s1 = srcs[e + 1], s2 = srcs[e + 2], s3 = srcs[e + 3];
            int s4 = srcs[e + 4], s5 = srcs[e + 5], s6 = srcs[e + 6], s7 = srcs[e + 7];
            float v0 = bf2f(xh[(size_t)s0 * 64 + lane]);
            float v1 = bf2f(xh[(size_t)s1 * 64 + lane]);
            float v2 = bf2f(xh[(size_t)s2 * 64 + lane]);
            float v3 = bf2f(xh[(size_t)s3 * 64 + lane]);
            float v4 = bf2f(xh[(size_t)s4 * 64 + lane]);
            float v5 = bf2f(xh[(size_t)s5 * 64 + lane]);
            float v6 = bf2f(xh[(size_t)s6 * 64 + lane]);
            float v7 = bf2f(xh[(size_t)s7 * 64 + lane]);
            a0 += v0; a1 += v1; a2 += v2; a3 += v3;
            a0 += v4; a1 += v5; a2 += v6; a3 += v7;
        }
        for (; e < e1; ++e)
            a0 += bf2f(xh[(size_t)srcs[e] * 64 + lane]);
        float acc = (a0 + a1) + (a2 + a3);
        int d = e1 - e0;
        A[nl][lane] = f2bf(acc * ((d > 0) ? (1.0f / (float)d) : 1.0f));
    }
    __syncthreads();

    const int r15 = lane & 15, g4 = lane >> 4;
    const int n0 = wid * 32;
    f32x4 acc[2][2] = {};
    for (int kk = 0; kk < 4; ++kk) {
        short8 b0 = *reinterpret_cast<const short8*>(Bp1 + (((kk * 128 + n0 + r15) * 4 + g4) << 3));
        short8 b1 = *reinterpret_cast<const short8*>(Bp1 + (((kk * 128 + n0 + 16 + r15) * 4 + g4) << 3));
        #pragma unroll
        for (int mt = 0; mt < 2; ++mt) {
            short8 a = *reinterpret_cast<const short8*>(&A[mt * 16 + r15][kk * 32 + g4 * 8]);
            acc[mt][0] = __builtin_amdgcn_mfma_f32_16x16x32_bf16(a, b0, acc[mt][0], 0, 0, 0);
            acc[mt][1] = __builtin_amdgcn_mfma_f32_16x16x32_bf16(a, b1, acc[mt][1], 0, 0, 0);
        }
    }
    #pragma unroll
    for (int mt = 0; mt < 2; ++mt)
        #pragma unroll
        for (int nt = 0; nt < 2; ++nt) {
            int col = n0 + nt * 16 + r15;
            float bb = b[col];
            #pragma unroll
            for (int reg = 0; reg < 4; ++reg) {
                int row = tile + mt * 16 + g4 * 4 + reg;
                h1h[(size_t)row * 128 + col] = f2bf(fmaxf(acc[mt][nt][reg] + bb, 0.0f));
            }
        }
}

// ================= layer 2 + heads: gather(bf16x2, unroll-8) + MFMA dense + relu + heads =================
__global__ __launch_bounds__(256, 8) void k_layer2(
    const unsigned int* __restrict__ h1h32,
    const int* __restrict__ rowpad, const int* __restrict__ srcs,
    const unsigned short* __restrict__ Bp2, const float* __restrict__ b,
    const float* __restrict__ Wh, const float* __restrict__ bh,
    const float* __restrict__ Wm, const float* __restrict__ bm,
    float* __restrict__ out1, float* __restrict__ out2)
{
    __shared__ unsigned short A[32][264];
    __shared__ int rs[33];
    const int tile = blockIdx.x * 32;
    const int tid = threadIdx.x, lane = tid & 63, wid = tid >> 6;

    if (tid < 33) rs[tid] = rowpad[(tile >> 8) * 257 + (tile & 255) + tid];
    {   // root rows -> cols 128..255
        int node = tid >> 3, part = tid & 7;
        const unsigned int* p = h1h32 + (size_t)(tile + node) * 64 + part * 8;
        uint4 v0 = *reinterpret_cast<const uint4*>(p);
        uint4 v1 = *reinterpret_cast<const uint4*>(p + 4);
        *reinterpret_cast<uint4*>(&A[node][128 + part * 16]) = v0;
        *reinterpret_cast<uint4*>(&A[node][128 + part * 16 + 8]) = v1;
    }
    __syncthreads();

    for (int it = 0; it < 8; ++it) {            // wave-per-node gather, unroll-8
        int nl = wid * 8 + it;
        int e0 = rs[nl], e1 = rs[nl + 1];
        float ax0 = 0.f, ax1 = 0.f, ax2 = 0.f, ax3 = 0.f;
        float ay0 = 0.f, ay1 = 0.f, ay2 = 0.f, ay3 = 0.f;
        int e = e0;
        for (; e + 8 <= e1; e += 8) {
            int s0 = srcs[e],     s1 = srcs[e + 1], s2 = srcs[e + 2], s3 = srcs[e + 3];
            int s4 = srcs[e + 4], s5 = srcs[e + 5], s6 = srcs[e + 6], s7 = srcs[e + 7];
            unsigned int u0 = h1h32[(size_t)s0 * 64 + lane];
            unsigned int u1 = h1h32[(size_t)s1 * 64 + lane];
            unsigned int u2 = h1h32[(size_t)s2 * 64 + lane];
            unsigned int u3 = h1h32[(size_t)s3 * 64 + lane];
            unsigned int u4 = h1h32[(size_t)s4 * 64 + lane];
            unsigned int u5 = h1h32[(size_t)s5 * 64 + lane];
            unsigned int u6 = h1h32[(size_t)s6 * 64 + lane];
            unsigned int u7 = h1h32[(size_t)s7 * 64 + lane];
            ax0 += bflo(u0); ay0 += bfhi(u0);
            ax1 += bflo(u1); ay1 += bfhi(u1);
            ax2 += bflo(u2); ay2 += bfhi(u2);
            ax3 += bflo(u3); ay3 += bfhi(u3);
            ax0 += bflo(u4); ay0 += bfhi(u4);
            ax1 += bflo(u5); ay1 += bfhi(u5);
            ax2 += bflo(u6); ay2 += bfhi(u6);
            ax3 += bflo(u7); ay3 += bfhi(u7);
        }
        for (; e < e1; ++e) {
            unsigned int u = h1h32[(size_t)srcs[e] * 64 + lane];
            ax0 += bflo(u); ay0 += bfhi(u);
        }
        float ax = (ax0 + ax1) + (ax2 + ax3);
        float ay = (ay0 + ay1) + (ay2 + ay3);
        int d = e1 - e0;
        float rd = (d > 0) ? (1.0f / (float)d) : 1.0f;
        unsigned int p = (unsigned int)f2bf(ax * rd) | ((unsigned int)f2bf(ay * rd) << 16);
        *reinterpret_cast<unsigned int*>(&A[nl][2 * lane]) = p;
    }
    __syncthreads();

    const int r15 = lane & 15, g4 = lane >> 4;
    const int n0 = wid * 32;
    f32x4 acc[2][2] = {};
    for (int kk = 0; kk < 8; ++kk) {
        short8 b0 = *reinterpret_cast<const short8*>(Bp2 + (((kk * 128 + n0 + r15) * 4 + g4) << 3));
        short8 b1 = *reinterpret_cast<const short8*>(Bp2 + (((kk * 128 + n0 + 16 + r15) * 4 + g4) << 3));
        #pragma unroll
        for (int mt = 0; mt < 2; ++mt) {
            short8 a = *reinterpret_cast<const short8*>(&A[mt * 16 + r15][kk * 32 + g4 * 8]);
            acc[mt][0] = __builtin_amdgcn_mfma_f32_16x16x32_bf16(a, b0, acc[mt][0], 0, 0, 0);
            acc[mt][1] = __builtin_amdgcn_mfma_f32_16x16x32_bf16(a, b1, acc[mt][1], 0, 0, 0);
        }
    }
    __syncthreads();
    float* h2L = reinterpret_cast<float*>(&A[0][0]);   // [32][132]
    #pragma unroll
    for (int mt = 0; mt < 2; ++mt)
        #pragma unroll
        for (int nt = 0; nt < 2; ++nt) {
            int col = n0 + nt * 16 + r15;
            float bb = b[col];
            #pragma unroll
            for (int reg = 0; reg < 4; ++reg) {
                int row = mt * 16 + g4 * 4 + reg;
                h2L[row * 132 + col] = fmaxf(acc[mt][nt][reg] + bb, 0.0f);
            }
        }
    __syncthreads();

    for (int t = tid; t < 352; t += 256) {       // heads
        int node = t / 11, o = t - node * 11;
        const float* h2 = &h2L[node * 132];
        if (o < 3) {
            float s = bh[o];
            for (int k = 0; k < 128; ++k) s += h2[k] * Wh[k * 3 + o];
            out1[(size_t)(tile + node) * 3 + o] = s;
        } else {
            int m = o - 3;
            float s = bm[m];
            for (int k = 0; k < 128; ++k) s += h2[k] * Wm[k * 8 + m];
            out2[(size_t)(tile + node) * 8 + m] = s;
        }
    }
}

extern "C" void kernel_launch(void* const* d_in, const int* in_sizes, int n_in,
                              void* d_out, int out_size, void* d_ws, size_t ws_size,
                              hipStream_t stream) {
    const float* x   = (const float*)d_in[0];
    const int*   ei  = (const int*)d_in[1];
    const int*   src = ei;
    const int*   dst = ei + N_EDGES;
    const float* Wl1 = (const float*)d_in[2];
    const float* Wr1 = (const float*)d_in[3];
    const float* b1  = (const float*)d_in[4];
    const float* Wl2 = (const float*)d_in[5];
    const float* Wr2 = (const float*)d_in[6];
    const float* b2  = (const float*)d_in[7];
    const float* Wh  = (const float*)d_in[8];
    const float* bh  = (const float*)d_in[9];
    const float* Wm  = (const float*)d_in[10];
    const float* bm  = (const float*)d_in[11];

    float* out1 = (float*)d_out;                   // [N,3]
    float* out2 = out1 + (size_t)N_NODES * 3;      // [N,8]

    char* ws = (char*)d_ws;
    int*   ccnt     = (int*)(ws);                            // 391 ints (counts, memset to 0)
    int*   rowpad   = (int*)(ws + (64 << 10));               // 391*257 ints (402KB)
    unsigned int* pairs = (unsigned int*)(ws + (1024 << 10)); // 391*8192 u32 (12.5MB)
    int*   srcs     = (int*)(ws + (14336 << 10));            // 391*8192 ints (12.5MB)
    unsigned short* xh  = (unsigned short*)(ws + (27648 << 10)); // 6.4M bf16 (12.8MB)
    unsigned short* h1h = (unsigned short*)(ws + (40960 << 10)); // 12.8M bf16 (25.6MB)
    unsigned short* Bp1 = (unsigned short*)(ws + (66560 << 10)); // 16384 bf16 (32KB)
    unsigned short* Bp2 = (unsigned short*)(ws + (66592 << 10)); // 32768 bf16 (64KB)

    hipMemsetAsync(ccnt, 0, NBUCK * sizeof(int), stream);
    k_pre<<<6540, 256, 0, stream>>>(x, xh, src, dst, ccnt, pairs, Wl1, Wr1, Wl2, Wr2, Bp1, Bp2);
    k_csr<<<NBUCK, 256, 0, stream>>>(ccnt, pairs, rowpad, srcs);

    k_layer1<<<3125, 256, 0, stream>>>(xh, rowpad, srcs, Bp1, b1, h1h);
    k_layer2<<<3125, 256, 0, stream>>>((const unsigned int*)h1h, rowpad, srcs,
                                       Bp2, b2, Wh, bh, Wm, bm, out1, out2);
}